// Round 12
// baseline (1027.706 us; speedup 1.0000x reference)
//
#include <hip/hip_runtime.h>

// AF-LSTM on MI355X. Sizes fixed: V=32000, D=H=512, B=64, T=256, A=4, 4H=2048.
// All float tensors f32; x,s int32; d_out f32 [64,512].
// R18/R19 (FAILED): G1-into-LSTM fusion regressed both times (601/636us vs
// 490+90 serial) -- latency-chain persistent kernel must not share CUs with a
// throughput GEMM. Reverted to R17 structure (best, 968us; LSTM 490us).
// R20: LSTM K-split. R12's LDS-port model: 8 waves x 16 redundant
// ds_read_b128 A-frag reads = ~2200cy of the 4590cy step. R13's fix (4
// waves, wfrag[4][16]=256 VGPR) spilled. K-split keeps 8 waves at UNCHANGED
// register cost: wave = (gate g, K-half kh); each wave does all 64 member
// cols over K in [kh*256,+256). wfrag[4][8] = 32 bf16x8 = same 128 VGPR;
// same 32 MFMA/wave; A-reads 16->8 per wave (128->64 b128/step, ~-1100cy
// port) at the cost of a second zl partial buffer (+16.6KB LDS, +~380cy).
// Gate math sums the two K-half partials. Everything else R17-identical.
// Exchange protocol UNCHANGED (relaxed-agent dword ops; sentinel 0xFFFFFFFF
// = bf16 NaN pair unreachable for sigmoid*tanh outputs).

typedef __bf16 bf16x8 __attribute__((ext_vector_type(8)));
typedef float f32x4 __attribute__((ext_vector_type(4)));

#define B_ 64
#define T_ 256
#define D_ 512
#define H4 2048
#define SENT 0xFFFFFFFFu

__device__ __forceinline__ unsigned short f2bf(float f) {
    unsigned u = __float_as_uint(f);
    u += 0x7fffu + ((u >> 16) & 1u);   // round-to-nearest-even
    return (unsigned short)(u >> 16);
}
__device__ __forceinline__ float bf2f(unsigned short x) {
    return __uint_as_float(((unsigned)x) << 16);
}
__device__ __forceinline__ float bf2f_lo(unsigned u) { return __uint_as_float(u << 16); }
__device__ __forceinline__ float bf2f_hi(unsigned u) { return __uint_as_float(u & 0xffff0000u); }

// fast transcendentals: v_exp_f32 and v_rcp_f32 (~1-2 ulp). h goes through
// bf16 (0.4% rel) every step anyway, so this is noise. Outputs stay in
// [0,1]/[-1,1] for all finite inputs, so the 0xFFFF sentinel is unreachable.
__device__ __forceinline__ float frcp(float x) { return __builtin_amdgcn_rcpf(x); }
__device__ __forceinline__ float fast_sigmoid(float x) {
    return frcp(1.f + __expf(-x));
}
__device__ __forceinline__ float fast_tanh(float x) {
    return 1.f - 2.f * frcp(1.f + __expf(2.f * x));
}

// ---------------------------------------------------------------------------
// prep_kernel: region-dispatch by blockIdx (256-thread blocks):
//   [0,2048)      : Hs sentinel fill (16 MiB of 0xFF)
//   [2048,3584)   : Wcat = bf16[W_ih | w_y | w_t]
//   [3584,7680)   : Ebf = bf16(embed[x])
//   [7680,7682)   : aspect normalization
// ---------------------------------------------------------------------------
__global__ __launch_bounds__(256)
void prep_kernel(const int* __restrict__ x,
                 const int* __restrict__ s,
                 const float* __restrict__ embed,
                 const float* __restrict__ Wih,
                 const float* __restrict__ wy,
                 const float* __restrict__ wt,
                 unsigned short* __restrict__ Wcat,
                 unsigned short* __restrict__ Ebf,
                 uint4* __restrict__ Hs4,
                 float* __restrict__ s_norm,
                 int use_ebf)
{
    __shared__ int sidx[256];
    const int bid = blockIdx.x;
    const int tid = threadIdx.x;

    if (bid < 2048) {
        const int i = (bid * 256 + tid) * 2;
        uint4 v = {SENT, SENT, SENT, SENT};
        Hs4[i] = v;
        Hs4[i + 1] = v;
    } else if (bid < 3584) {
        const int i = ((bid - 2048) * 256 + tid) * 4;
        const float* src; int off;
        if (i < 1048576)      { src = Wih; off = 0; }
        else if (i < 1310720) { src = wy;  off = 1048576; }
        else                  { src = wt;  off = 1310720; }
        float4 v = *(const float4*)(src + (i - off));
        unsigned short o[4] __attribute__((aligned(8)));
        o[0] = f2bf(v.x); o[1] = f2bf(v.y); o[2] = f2bf(v.z); o[3] = f2bf(v.w);
        *(unsigned long long*)(Wcat + i) = *(const unsigned long long*)o;
    } else if (bid < 7680) {
        if (!use_ebf) return;
        const long i = ((long)(bid - 3584) * 256 + tid) * 8;
        const int row = (int)(i >> 9);
        const int col = (int)(i & 511);
        const float* src = embed + (long)x[row] * 512 + col;
        float4 u0 = *(const float4*)(src);
        float4 u1 = *(const float4*)(src + 4);
        unsigned short o[8] __attribute__((aligned(16)));
        o[0] = f2bf(u0.x); o[1] = f2bf(u0.y); o[2] = f2bf(u0.z); o[3] = f2bf(u0.w);
        o[4] = f2bf(u1.x); o[5] = f2bf(u1.y); o[6] = f2bf(u1.z); o[7] = f2bf(u1.w);
        *(uint4*)(Ebf + i) = *(const uint4*)o;
    } else {
        const int d = (bid - 7680) * 256 + tid;
        sidx[tid] = s[tid];
        __syncthreads();
        float sum = 0.f, sq = 0.f;
        for (int i = 0; i < 256; i++) {
            float v = embed[(long)sidx[i] * D_ + d];
            sum += v; sq += v * v;
        }
        float mu = sum * (1.f / 256.f);
        float var = sq * (1.f / 256.f) - mu * mu;
        float rstd = rsqrtf(var + 1e-5f);
        for (int b = 0; b < 64; b++) {
            float acc = 0.f;
            #pragma unroll
            for (int a = 0; a < 4; a++) {
                acc += embed[(long)sidx[b * 4 + a] * D_ + d] - mu;
            }
            s_norm[b * D_ + d] = acc * rstd;
        }
    }
}

// ---------------------------------------------------------------------------
// C = A @ B^T GEMM, bf16 MFMA 16x16x32. 128x128 block tile, 4 waves, each
// wave a 64x64 sub-tile as 4x4 fragments. (G1/G2/G3/G4; R17-identical)
// ---------------------------------------------------------------------------
__global__ __launch_bounds__(256)
void gemm_bt(const void* __restrict__ Abase, int a_f32,
             const int* __restrict__ gather_idx,
             const unsigned short* __restrict__ Bmat_h,
             const float* __restrict__ circ_src,
             const float* __restrict__ bias,
             unsigned short* __restrict__ outb,
             float* __restrict__ outf,
             int N, int K,
             long A_bstride, long out_bstride,
             int act)
{
    __shared__ __align__(16) unsigned short Asm[128 * 40];
    __shared__ __align__(16) unsigned short Bsm[128 * 40];

    const int bz = blockIdx.z;
    const int tile_n = blockIdx.x * 128;
    const int tile_m = blockIdx.y * 128;
    const int tid = threadIdx.x;
    const int lane = tid & 63;
    const int w = tid >> 6;
    const int wm = (w >> 1) * 64;
    const int wn = (w & 1) * 64;

    const int srow = tid >> 1;
    const int skc = (tid & 1) * 16;

    const float* arow_f = nullptr;
    const unsigned short* arow_h = nullptr;
    if (a_f32) {
        const float* Af = (const float*)Abase;
        if (gather_idx) arow_f = Af + (long)gather_idx[tile_m + srow] * K;
        else            arow_f = Af + (long)bz * A_bstride + (long)(tile_m + srow) * K;
    } else {
        arow_h = (const unsigned short*)Abase + (long)bz * A_bstride + (long)(tile_m + srow) * K;
    }
    const unsigned short* brow_h = nullptr;
    const float* csrc = nullptr;
    if (circ_src) csrc = circ_src + bz * 512;
    else brow_h = Bmat_h + (long)(tile_n + srow) * K;

    f32x4 zero4 = {0.f, 0.f, 0.f, 0.f};
    f32x4 acc[4][4];
    #pragma unroll
    for (int mi = 0; mi < 4; mi++)
        #pragma unroll
        for (int ni = 0; ni < 4; ni++) acc[mi][ni] = zero4;

    const int fr = lane & 15;
    const int fq = (lane >> 4) * 8;

    for (int kc = 0; kc < K; kc += 32) {
        __syncthreads();
        if (a_f32) {
            float4 u0 = *(const float4*)(arow_f + kc + skc);
            float4 u1 = *(const float4*)(arow_f + kc + skc + 4);
            float4 u2 = *(const float4*)(arow_f + kc + skc + 8);
            float4 u3 = *(const float4*)(arow_f + kc + skc + 12);
            unsigned short tmp[16] __attribute__((aligned(16)));
            tmp[0] = f2bf(u0.x); tmp[1] = f2bf(u0.y); tmp[2]  = f2bf(u0.z); tmp[3]  = f2bf(u0.w);
            tmp[4] = f2bf(u1.x); tmp[5] = f2bf(u1.y); tmp[6]  = f2bf(u1.z); tmp[7]  = f2bf(u1.w);
            tmp[8] = f2bf(u2.x); tmp[9] = f2bf(u2.y); tmp[10] = f2bf(u2.z); tmp[11] = f2bf(u2.w);
            tmp[12] = f2bf(u3.x); tmp[13] = f2bf(u3.y); tmp[14] = f2bf(u3.z); tmp[15] = f2bf(u3.w);
            *(uint4*)&Asm[srow * 40 + skc]     = *(const uint4*)tmp;
            *(uint4*)&Asm[srow * 40 + skc + 8] = *(const uint4*)(tmp + 8);
        } else {
            *(uint4*)&Asm[srow * 40 + skc]     = *(const uint4*)(arow_h + kc + skc);
            *(uint4*)&Asm[srow * 40 + skc + 8] = *(const uint4*)(arow_h + kc + skc + 8);
        }
        if (csrc) {
            unsigned short tmp[16] __attribute__((aligned(16)));
            int n_abs = tile_n + srow;
            #pragma unroll
            for (int j = 0; j < 16; j++) {
                int k_abs = kc + skc + j;
                tmp[j] = f2bf(csrc[(k_abs - n_abs) & 511]);
            }
            *(uint4*)&Bsm[srow * 40 + skc]     = *(const uint4*)tmp;
            *(uint4*)&Bsm[srow * 40 + skc + 8] = *(const uint4*)(tmp + 8);
        } else {
            *(uint4*)&Bsm[srow * 40 + skc]     = *(const uint4*)(brow_h + kc + skc);
            *(uint4*)&Bsm[srow * 40 + skc + 8] = *(const uint4*)(brow_h + kc + skc + 8);
        }
        __syncthreads();
        bf16x8 av[4], bv[4];
        #pragma unroll
        for (int mi = 0; mi < 4; mi++)
            av[mi] = *(const bf16x8*)&Asm[(wm + mi * 16 + fr) * 40 + fq];
        #pragma unroll
        for (int ni = 0; ni < 4; ni++)
            bv[ni] = *(const bf16x8*)&Bsm[(wn + ni * 16 + fr) * 40 + fq];
        #pragma unroll
        for (int mi = 0; mi < 4; mi++)
            #pragma unroll
            for (int ni = 0; ni < 4; ni++)
                acc[mi][ni] = __builtin_amdgcn_mfma_f32_16x16x32_bf16(
                    av[mi], bv[ni], acc[mi][ni], 0, 0, 0);
    }

    #pragma unroll
    for (int mi = 0; mi < 4; mi++) {
        #pragma unroll
        for (int ni = 0; ni < 4; ni++) {
            #pragma unroll
            for (int rg = 0; rg < 4; rg++) {
                int row = tile_m + wm + mi * 16 + (lane >> 4) * 4 + rg;
                int col = tile_n + wn + ni * 16 + (lane & 15);
                float v = acc[mi][ni][rg];
                if (bias) v += bias[col];
                if (act == 1) v = fast_tanh(v);
                long oidx = (long)bz * out_bstride + (long)row * N + col;
                if (outb) outb[oidx] = f2bf(v);
                else outf[oidx] = v;
            }
        }
    }
}

// ---------------------------------------------------------------------------
// Persistent LSTM recurrence, 64 blocks x 512 threads (8 waves). R20 K-split:
// clique cq = bid&7 (XCD-local), member nbp = bid>>3 owns h-cols [nbp*64,+64).
// Wave w = (gate g = w>>1, K-half kh = w&1): computes ALL 64 member cols of
// gate g over K in [kh*256,+256). wfrag[4][8] = 32 bf16x8 = 128 VGPR (same
// budget as R12's wfrag[2][16]). A-frag reads 8/wave (was 16) -> 64 b128/step
// total (was 128). Partials scattered to zl[kh]; gate math sums both halves.
// Poll/publish/sentinel protocol R12/R17-exact.
// ---------------------------------------------------------------------------
#define WSTRIDE 520
#define ZL2(kh,g,r,d) zl[((((kh)*4+(g))*8+(r))*65)+(d)]

__global__ __launch_bounds__(512, 2)
void persistent_lstm(const float* __restrict__ Whh,         // f32 [2048][512]
                     const unsigned short* __restrict__ Zx, // bf16 [16384][2048]
                     unsigned int* __restrict__ Hsu)        // Hs as dwords [64*256*256]
{
    __shared__ __align__(16) unsigned short hsm[16 * WSTRIDE];  // 16,640 B
    __shared__ float zl[2 * 4 * 8 * 65];                        // 16,640 B

    const int cq  = blockIdx.x & 7;   // clique id (== XCD under RR dispatch)
    const int nbp = blockIdx.x >> 3;  // column-owner within clique, 0..7
    const int tid = threadIdx.x;
    const int w = tid >> 6;        // 0..7
    const int lane = tid & 63;
    const int fr = lane & 15;
    const int fq = (lane >> 4) * 8;
    const int g  = w >> 1;         // gate 0..3 (i,f,g,o)
    const int kh = w & 1;          // K-half 0..1

    // ---- one-time: wfrag[n][c] = W_hh rows (gate g, col frag n) over the
    //      wave's K-half. 4 frags x 8 chunks = 32 bf16x8 = 128 VGPR.
    bf16x8 wfrag[4][8];
    #pragma unroll
    for (int n = 0; n < 4; n++) {
        const float* wrow = Whh + (long)(g * 512 + nbp * 64 + n * 16 + fr) * 512;
        #pragma unroll
        for (int c = 0; c < 8; c++) {
            int k0 = kh * 256 + c * 32 + fq;
            float4 u0 = *(const float4*)(wrow + k0);
            float4 u1 = *(const float4*)(wrow + k0 + 4);
            unsigned short tmp[8] __attribute__((aligned(16)));
            tmp[0] = f2bf(u0.x); tmp[1] = f2bf(u0.y); tmp[2] = f2bf(u0.z); tmp[3] = f2bf(u0.w);
            tmp[4] = f2bf(u1.x); tmp[5] = f2bf(u1.y); tmp[6] = f2bf(u1.z); tmp[7] = f2bf(u1.w);
            wfrag[n][c] = *(const bf16x8*)tmp;
        }
    }

    // zero hsm once (rows 8..15 stay zero = MFMA pad rows). Visible to all
    // threads after the first barrier (S2 of t=0) before any hsm read (t=1).
    for (int i = tid; i < 16 * WSTRIDE / 2; i += 512)
        ((unsigned*)hsm)[i] = 0;

    // poll/staging ownership (R8-formula, 4 dwords): idx = k*512+tid,
    // row pr = idx>>8 (0..7), dword dp = idx&255
    int st_r[4], st_dp[4];
    #pragma unroll
    for (int k = 0; k < 4; k++) {
        int idx = k * 512 + tid;
        st_r[k] = idx >> 8;
        st_dp[k] = idx & 255;
    }

    // gate-math ownership (threads 0..255): batch grow 0..7, col pair d0
    const int grow = (tid & 255) >> 5;
    const int d0 = (tid & 31) * 2;
    const int b_own = cq * 8 + grow;
    const int dg = nbp * 64 + d0;
    float ca = 0.f, cb = 0.f;      // cell state in registers (threads < 256)

    f32x4 zero4 = {0.f, 0.f, 0.f, 0.f};

    for (int t = 0; t < T_; t++) {
        // Zx gate pre-activations: independent of h -> issue early
        unsigned zi_u = 0, zf_u = 0, zg_u = 0, zo_u = 0;
        if (tid < 256) {
            const long zb = ((long)b_own * T_ + t) * H4 + dg;
            zi_u = *(const unsigned*)&Zx[zb + 0 * 512];
            zf_u = *(const unsigned*)&Zx[zb + 1 * 512];
            zg_u = *(const unsigned*)&Zx[zb + 2 * 512];
            zo_u = *(const unsigned*)&Zx[zb + 3 * 512];
        }

        f32x4 an[4] = {zero4, zero4, zero4, zero4};
        if (t > 0) {
            // poll-stage h_{t-1}: 2048 dwords of Hs[cq*8..+8][t-1][*]
            unsigned vv[4];
            long ad[4];
            #pragma unroll
            for (int k = 0; k < 4; k++) {
                ad[k] = ((long)(cq * 8 + st_r[k]) * T_ + (t - 1)) * 256 + st_dp[k];
                vv[k] = __hip_atomic_load(Hsu + ad[k], __ATOMIC_RELAXED,
                                          __HIP_MEMORY_SCOPE_AGENT);
            }
            // check current values; if any pending, reload ALL (grouped) and
            // re-check the freshly loaded values in the same round.
            while (true) {
                bool pend = false;
                #pragma unroll
                for (int k = 0; k < 4; k++) pend |= (vv[k] == SENT);
                if (!__ballot(pend)) break;
                #pragma unroll
                for (int k = 0; k < 4; k++) {
                    vv[k] = __hip_atomic_load(Hsu + ad[k], __ATOMIC_RELAXED,
                                              __HIP_MEMORY_SCOPE_AGENT);
                }
            }
            #pragma unroll
            for (int k = 0; k < 4; k++) {
                *(unsigned*)&hsm[st_r[k] * WSTRIDE + st_dp[k] * 2] = vv[k];
            }
            __syncthreads();   // S1: hsm staged (also fences prev-iter zl reads)
            // partial z = h_{t-1}[16x256 K-half] @ Wfrags^T : 8 shared A
            // loads, 4 col-frags, 2 indep chains per frag (8 chains total)
            const unsigned short* arow = hsm + fr * WSTRIDE + kh * 256;
            f32x4 acf[4][2];
            #pragma unroll
            for (int n = 0; n < 4; n++) { acf[n][0] = zero4; acf[n][1] = zero4; }
            #pragma unroll
            for (int c = 0; c < 8; c += 2) {
                bf16x8 x0 = *(const bf16x8*)(arow + (c + 0) * 32 + fq);
                bf16x8 x1 = *(const bf16x8*)(arow + (c + 1) * 32 + fq);
                #pragma unroll
                for (int n = 0; n < 4; n++) {
                    acf[n][0] = __builtin_amdgcn_mfma_f32_16x16x32_bf16(x0, wfrag[n][c + 0], acf[n][0], 0, 0, 0);
                    acf[n][1] = __builtin_amdgcn_mfma_f32_16x16x32_bf16(x1, wfrag[n][c + 1], acf[n][1], 0, 0, 0);
                }
            }
            #pragma unroll
            for (int n = 0; n < 4; n++) an[n] = acf[n][0] + acf[n][1];
        }
        // scatter partial z to zl[kh] (C/D: col=lane&15, row=(lane>>4)*4+reg);
        // only batch rows 0..7 are real -> lanes 0..31
        if (lane < 32) {
            const int rb = (lane >> 4) * 4;           // 0 or 4
            const int cl = lane & 15;
            #pragma unroll
            for (int n = 0; n < 4; n++) {
                #pragma unroll
                for (int rg = 0; rg < 4; rg++) {
                    ZL2(kh, g, rb + rg, n * 16 + cl) = an[n][rg];
                }
            }
        }
        __syncthreads();       // S2: zl complete (and hsm reads drained)
        // gate math on threads 0..255: sum the two K-half partials + Zx
        if (tid < 256) {
            float zi0 = ZL2(0, 0, grow, d0)     + ZL2(1, 0, grow, d0)     + bf2f_lo(zi_u);
            float zi1 = ZL2(0, 0, grow, d0 + 1) + ZL2(1, 0, grow, d0 + 1) + bf2f_hi(zi_u);
            float zf0 = ZL2(0, 1, grow, d0)     + ZL2(1, 1, grow, d0)     + bf2f_lo(zf_u);
            float zf1 = ZL2(0, 1, grow, d0 + 1) + ZL2(1, 1, grow, d0 + 1) + bf2f_hi(zf_u);
            float zg0 = ZL2(0, 2, grow, d0)     + ZL2(1, 2, grow, d0)     + bf2f_lo(zg_u);
            float zg1 = ZL2(0, 2, grow, d0 + 1) + ZL2(1, 2, grow, d0 + 1) + bf2f_hi(zg_u);
            float zo0 = ZL2(0, 3, grow, d0)     + ZL2(1, 3, grow, d0)     + bf2f_lo(zo_u);
            float zo1 = ZL2(0, 3, grow, d0 + 1) + ZL2(1, 3, grow, d0 + 1) + bf2f_hi(zo_u);

            ca = fast_sigmoid(zf0) * ca + fast_sigmoid(zi0) * fast_tanh(zg0);
            cb = fast_sigmoid(zf1) * cb + fast_sigmoid(zi1) * fast_tanh(zg1);
            float h0 = fast_sigmoid(zo0) * fast_tanh(ca);
            float h1 = fast_sigmoid(zo1) * fast_tanh(cb);

            unsigned hp = (unsigned)f2bf(h0) | ((unsigned)f2bf(h1) << 16);
            // publish: history and exchange in one store (write-through)
            __hip_atomic_store(Hsu + ((long)b_own * T_ + t) * 256 + nbp * 32 + (tid & 31),
                               hp, __ATOMIC_RELAXED, __HIP_MEMORY_SCOPE_AGENT);
        }
        // no trailing sync: S1 of the next iteration protects zl reuse
    }
}

// ---------------------------------------------------------------------------
// tail_kernel: fused attn_r + hstar + out (R17-identical)
// ---------------------------------------------------------------------------
__global__ __launch_bounds__(256)
void tail_kernel(const float* __restrict__ apre,
                 const unsigned short* __restrict__ Hs,
                 const float* __restrict__ w_p,
                 const float* __restrict__ w_x,
                 const float* __restrict__ w_f,
                 const float* __restrict__ b_f,
                 float* __restrict__ out)
{
    __shared__ __align__(16) float apc[16 * 512];
    __shared__ __align__(16) unsigned short hc[16 * 512];
    __shared__ float rs[512];
    __shared__ float hts[512];
    __shared__ float hsr[512];
    __shared__ float lg[512];
    __shared__ float red[8];

    const int b = blockIdx.x, tid = threadIdx.x;
    const int d1 = tid + 256;
    const float* apb = apre + (long)b * T_ * D_;
    const unsigned short* hpb = Hs + (long)b * T_ * D_;

    float mx0 = -3.0e38f, sm0 = 0.f, ac0 = 0.f;
    float mx1 = -3.0e38f, sm1 = 0.f, ac1 = 0.f;

    for (int t0 = 0; t0 < T_; t0 += 16) {
        __syncthreads();
        for (int idx = tid; idx < 16 * 128; idx += 256) {
            int rr = idx >> 7, cc = (idx & 127) * 4;
            *(float4*)&apc[rr * 512 + cc] = *(const float4*)(apb + (long)(t0 + rr) * 512 + cc);
        }
        for (int idx = tid; idx < 16 * 64; idx += 256) {
            int rr = idx >> 6, cc = (idx & 63) * 8;
            *(uint4*)&hc[rr * 512 + cc] = *(const uint4*)(hpb + (long)(t0 + rr) * 512 + cc);
        }
        __syncthreads();
        #pragma unroll
        for (int i = 0; i < 16; i++) {
            float v0 = apc[i * 512 + tid];
            float h0 = bf2f(hc[i * 512 + tid]);
            if (v0 > mx0) {
                float fct = __expf(mx0 - v0);
                sm0 = sm0 * fct + 1.f;
                ac0 = ac0 * fct + h0;
                mx0 = v0;
            } else {
                float e = __expf(v0 - mx0);
                sm0 += e;
                ac0 += e * h0;
            }
            float v1 = apc[i * 512 + d1];
            float h1 = bf2f(hc[i * 512 + d1]);
            if (v1 > mx1) {
                float fct = __expf(mx1 - v1);
                sm1 = sm1 * fct + 1.f;
                ac1 = ac1 * fct + h1;
                mx1 = v1;
            } else {
                float e = __expf(v1 - mx1);
                sm1 += e;
                ac1 += e * h1;
            }
        }
    }
    rs[tid] = ac0 / sm0;
    rs[d1]  = ac1 / sm1;
    const long hlast = ((long)b * T_ + (T_ - 1)) * D_;
    hts[tid] = bf2f(Hs[hlast + tid]);
    hts[d1]  = bf2f(Hs[hlast + d1]);
    __syncthreads();

    for (int d = tid; d < 512; d += 256) {
        const float* wp = w_p + (long)d * D_;
        const float* wx = w_x + (long)d * D_;
        float acc = 0.f;
        for (int e = 0; e < 512; e += 4) {
            float4 p1 = *(const float4*)(wp + e);
            float4 p2 = *(const float4*)(wx + e);
            acc += p1.x * rs[e] + p1.y * rs[e + 1] + p1.z * rs[e + 2] + p1.w * rs[e + 3];
            acc += p2.x * hts[e] + p2.y * hts[e + 1] + p2.z * hts[e + 2] + p2.w * hts[e + 3];
        }
        hsr[d] = fast_tanh(acc);
    }
    __syncthreads();

    for (int d = tid; d < 512; d += 256) {
        const float* wr = w_f + (long)d * D_;
        float acc = b_f[d];
        for (int e = 0; e < 512; e += 4) {
            float4 p = *(const float4*)(wr + e);
            acc += p.x * hsr[e] + p.y * hsr[e + 1] + p.z * hsr[e + 2] + p.w * hsr[e + 3];
        }
        lg[d] = acc;
    }
    __syncthreads();
    float m0 = fmaxf(lg[tid], lg[d1]);
    for (int off = 32; off > 0; off >>= 1) m0 = fmaxf(m0, __shfl_down(m0, off, 64));
    if ((tid & 63) == 0) red[tid >> 6] = m0;
    __syncthreads();
    float bmax = fmaxf(fmaxf(red[0], red[1]), fmaxf(red[2], red[3]));
    float e0 = __expf(lg[tid] - bmax);
    float e1 = __expf(lg[d1] - bmax);
    float s0 = e0 + e1;
    for (int off = 32; off > 0; off >>= 1) s0 += __shfl_down(s0, off, 64);
    if ((tid & 63) == 0) red[4 + (tid >> 6)] = s0;
    __syncthreads();
    float inv = 1.f / (red[4] + red[5] + red[6] + red[7]);
    out[b * D_ + tid] = e0 * inv;
    out[b * D_ + d1]  = e1 * inv;
}

// ---------------------------------------------------------------------------
extern "C" void kernel_launch(void* const* d_in, const int* in_sizes, int n_in,
                              void* d_out, int out_size, void* d_ws, size_t ws_size,
                              hipStream_t stream)
{
    (void)in_sizes; (void)n_in; (void)out_size;

    const int* x = (const int*)d_in[0];
    const int* s = (const int*)d_in[1];
    const float* embed  = (const float*)d_in[2];
    const float* W_ih   = (const float*)d_in[3];
    const float* W_hh   = (const float*)d_in[4];
    const float* b_lstm = (const float*)d_in[5];
    const float* w_y = (const float*)d_in[6];
    const float* w_t = (const float*)d_in[7];
    const float* w_p = (const float*)d_in[8];
    const float* w_x = (const float*)d_in[9];
    const float* w_f = (const float*)d_in[10];
    const float* b_f = (const float*)d_in[11];

    // Workspace (overlaid):
    //   [0,64MiB)   phase1: Zx bf16 [16384][2048]
    //               phase2: apre f32 @0, mbuf bf16 @32MiB, Ybuf bf16 @48MiB
    //   [64MiB,+16MiB) Hs bf16 (exchange; sentinel-filled)
    //   @86114304: s_norm
    //   @86507520: Wcat_bf = bf16 [W_ih | w_y | w_t]  (3 MiB)
    //   @89653248: Ebf bf16 [16384][512] (16 MiB) -- only if ws_size allows
    char* ws = (char*)d_ws;
    unsigned short* Zx   = (unsigned short*)(ws + 0);
    float*          apre = (float*)(ws + 0);
    unsigned short* mbuf = (unsigned short*)(ws + 33554432);
    unsigned short* Ybuf = (unsigned short*)(ws + 50331648);
    unsigned short* Hs   = (unsigned short*)(ws + 67108864);
    float* s_norm = (float*)(ws + 86114304);
    unsigned short* Wcat = (unsigned short*)(ws + 86507520);
    unsigned short* Wih_bf = Wcat;
    unsigned short* wy_bf  = Wcat + 1048576;
    unsigned short* wt_bf  = Wcat + 1310720;
    unsigned short* Ebf  = (unsigned short*)(ws + 89653248);
    const int use_ebf = (ws_size >= (size_t)89653248 + 16777216u);

    // 0) fused prep: Hs sentinel fill | weight conv | embed gather-conv |
    //    aspect norm. One launch, 7682 blocks.
    prep_kernel<<<dim3(7682), dim3(256), 0, stream>>>(
        x, s, embed, W_ih, w_y, w_t, Wcat, Ebf, (uint4*)Hs, s_norm, use_ebf);

    // 1) G1: Zx = embed[x] @ W_ih^T + b_lstm  (M=16384, N=2048, K=512)
    if (use_ebf)
        gemm_bt<<<dim3(16, 128, 1), dim3(256), 0, stream>>>(
            Ebf, 0, nullptr, Wih_bf, nullptr, b_lstm, Zx, nullptr,
            2048, 512, 0L, 0L, 0);
    else
        gemm_bt<<<dim3(16, 128, 1), dim3(256), 0, stream>>>(
            embed, 1, x, Wih_bf, nullptr, b_lstm, Zx, nullptr,
            2048, 512, 0L, 0L, 0);

    // 2) recurrence: ONE persistent kernel, 64 blocks x 512 threads
    persistent_lstm<<<dim3(64), dim3(512), 0, stream>>>(
        W_hh, Zx, (unsigned int*)Hs);

    // ---- phase 2: Zx dead; region reused for apre/mbuf/Ybuf ----

    // 3) G2: m[b] = Hs[b] @ circ(s_norm[b])^T  (M=256, N=512, K=512, 64 batches)
    gemm_bt<<<dim3(4, 2, 64), dim3(256), 0, stream>>>(
        Hs, 0, nullptr, nullptr, s_norm, nullptr, mbuf, nullptr,
        512, 512, (long)(T_ * D_), (long)(T_ * D_), 0);

    // 4) G3: Y = tanh(m @ w_y^T)  (M=16384, N=512, K=512)
    gemm_bt<<<dim3(4, 128, 1), dim3(256), 0, stream>>>(
        mbuf, 0, nullptr, wy_bf, nullptr, nullptr, Ybuf, nullptr,
        512, 512, 0L, 0L, 1);

    // 5) G4: apre = Y @ w_t^T
    gemm_bt<<<dim3(4, 128, 1), dim3(256), 0, stream>>>(
        Ybuf, 0, nullptr, wt_bf, nullptr, nullptr, nullptr, apre,
        512, 512, 0L, 0L, 0);

    // 6) fused tail: online softmax+r, h_star, logits+softmax (1 block/batch)
    tail_kernel<<<dim3(64), dim3(256), 0, stream>>>(
        apre, Hs, w_p, w_x, w_f, b_f, (float*)d_out);
}

// Round 13
// 967.398 us; speedup vs baseline: 1.0623x; 1.0623x over previous
//
#include <hip/hip_runtime.h>

// AF-LSTM on MI355X. Sizes fixed: V=32000, D=H=512, B=64, T=256, A=4, 4H=2048.
// All float tensors f32; x,s int32; d_out f32 [64,512].
// R20 (REGRESSED, LSTM 553us): K-split halved A-frag reads + cut conflicts
// 10.45M->8.37M yet LOST 60us -> LDS-port model FALSIFIED. The R12-shape
// step is exchange-RT + straggler-skew bound. 488-494us reproduced 4x
// (R12/R14/R16/R17); five attempts to beat it all regressed (R13 spill,
// R18/R19 fusion, R20 K-split).
// R21: revert to best-known = R17 structure with R12-exact persistent_lstm.
// prep fused (Hs fill | Wcat | Ebf | aspect), G1 via Ebf bf16, gemm_bt 128^2
// for G1-G4, fused online-softmax tail. Expected ~968us total.
// Exchange protocol (proven): publishers store h into Hs via relaxed-agent
// dword atomics (write-through); Hs pre-filled 0xFFFFFFFF (bf16 NaN pair,
// unreachable for sigmoid*tanh outputs); consumers grouped-poll exactly the
// dwords they need, re-checking freshly loaded values in the same round.

typedef __bf16 bf16x8 __attribute__((ext_vector_type(8)));
typedef float f32x4 __attribute__((ext_vector_type(4)));

#define B_ 64
#define T_ 256
#define D_ 512
#define H4 2048
#define SENT 0xFFFFFFFFu

__device__ __forceinline__ unsigned short f2bf(float f) {
    unsigned u = __float_as_uint(f);
    u += 0x7fffu + ((u >> 16) & 1u);   // round-to-nearest-even
    return (unsigned short)(u >> 16);
}
__device__ __forceinline__ float bf2f(unsigned short x) {
    return __uint_as_float(((unsigned)x) << 16);
}
__device__ __forceinline__ float bf2f_lo(unsigned u) { return __uint_as_float(u << 16); }
__device__ __forceinline__ float bf2f_hi(unsigned u) { return __uint_as_float(u & 0xffff0000u); }

// fast transcendentals: v_exp_f32 and v_rcp_f32 (~1-2 ulp). h goes through
// bf16 (0.4% rel) every step anyway, so this is noise. Outputs stay in
// [0,1]/[-1,1] for all finite inputs, so the 0xFFFF sentinel is unreachable.
__device__ __forceinline__ float frcp(float x) { return __builtin_amdgcn_rcpf(x); }
__device__ __forceinline__ float fast_sigmoid(float x) {
    return frcp(1.f + __expf(-x));
}
__device__ __forceinline__ float fast_tanh(float x) {
    return 1.f - 2.f * frcp(1.f + __expf(2.f * x));
}

// ---------------------------------------------------------------------------
// prep_kernel: region-dispatch by blockIdx (256-thread blocks):
//   [0,2048)      : Hs sentinel fill (16 MiB of 0xFF)
//   [2048,3584)   : Wcat = bf16[W_ih | w_y | w_t]
//   [3584,7680)   : Ebf = bf16(embed[x])
//   [7680,7682)   : aspect normalization
// ---------------------------------------------------------------------------
__global__ __launch_bounds__(256)
void prep_kernel(const int* __restrict__ x,
                 const int* __restrict__ s,
                 const float* __restrict__ embed,
                 const float* __restrict__ Wih,
                 const float* __restrict__ wy,
                 const float* __restrict__ wt,
                 unsigned short* __restrict__ Wcat,
                 unsigned short* __restrict__ Ebf,
                 uint4* __restrict__ Hs4,
                 float* __restrict__ s_norm,
                 int use_ebf)
{
    __shared__ int sidx[256];
    const int bid = blockIdx.x;
    const int tid = threadIdx.x;

    if (bid < 2048) {
        const int i = (bid * 256 + tid) * 2;
        uint4 v = {SENT, SENT, SENT, SENT};
        Hs4[i] = v;
        Hs4[i + 1] = v;
    } else if (bid < 3584) {
        const int i = ((bid - 2048) * 256 + tid) * 4;
        const float* src; int off;
        if (i < 1048576)      { src = Wih; off = 0; }
        else if (i < 1310720) { src = wy;  off = 1048576; }
        else                  { src = wt;  off = 1310720; }
        float4 v = *(const float4*)(src + (i - off));
        unsigned short o[4] __attribute__((aligned(8)));
        o[0] = f2bf(v.x); o[1] = f2bf(v.y); o[2] = f2bf(v.z); o[3] = f2bf(v.w);
        *(unsigned long long*)(Wcat + i) = *(const unsigned long long*)o;
    } else if (bid < 7680) {
        if (!use_ebf) return;
        const long i = ((long)(bid - 3584) * 256 + tid) * 8;
        const int row = (int)(i >> 9);
        const int col = (int)(i & 511);
        const float* src = embed + (long)x[row] * 512 + col;
        float4 u0 = *(const float4*)(src);
        float4 u1 = *(const float4*)(src + 4);
        unsigned short o[8] __attribute__((aligned(16)));
        o[0] = f2bf(u0.x); o[1] = f2bf(u0.y); o[2] = f2bf(u0.z); o[3] = f2bf(u0.w);
        o[4] = f2bf(u1.x); o[5] = f2bf(u1.y); o[6] = f2bf(u1.z); o[7] = f2bf(u1.w);
        *(uint4*)(Ebf + i) = *(const uint4*)o;
    } else {
        const int d = (bid - 7680) * 256 + tid;
        sidx[tid] = s[tid];
        __syncthreads();
        float sum = 0.f, sq = 0.f;
        for (int i = 0; i < 256; i++) {
            float v = embed[(long)sidx[i] * D_ + d];
            sum += v; sq += v * v;
        }
        float mu = sum * (1.f / 256.f);
        float var = sq * (1.f / 256.f) - mu * mu;
        float rstd = rsqrtf(var + 1e-5f);
        for (int b = 0; b < 64; b++) {
            float acc = 0.f;
            #pragma unroll
            for (int a = 0; a < 4; a++) {
                acc += embed[(long)sidx[b * 4 + a] * D_ + d] - mu;
            }
            s_norm[b * D_ + d] = acc * rstd;
        }
    }
}

// ---------------------------------------------------------------------------
// C = A @ B^T GEMM, bf16 MFMA 16x16x32. 128x128 block tile, 4 waves, each
// wave a 64x64 sub-tile as 4x4 fragments. (G1/G2/G3/G4)
// ---------------------------------------------------------------------------
__global__ __launch_bounds__(256)
void gemm_bt(const void* __restrict__ Abase, int a_f32,
             const int* __restrict__ gather_idx,
             const unsigned short* __restrict__ Bmat_h,
             const float* __restrict__ circ_src,
             const float* __restrict__ bias,
             unsigned short* __restrict__ outb,
             float* __restrict__ outf,
             int N, int K,
             long A_bstride, long out_bstride,
             int act)
{
    __shared__ __align__(16) unsigned short Asm[128 * 40];
    __shared__ __align__(16) unsigned short Bsm[128 * 40];

    const int bz = blockIdx.z;
    const int tile_n = blockIdx.x * 128;
    const int tile_m = blockIdx.y * 128;
    const int tid = threadIdx.x;
    const int lane = tid & 63;
    const int w = tid >> 6;
    const int wm = (w >> 1) * 64;
    const int wn = (w & 1) * 64;

    const int srow = tid >> 1;
    const int skc = (tid & 1) * 16;

    const float* arow_f = nullptr;
    const unsigned short* arow_h = nullptr;
    if (a_f32) {
        const float* Af = (const float*)Abase;
        if (gather_idx) arow_f = Af + (long)gather_idx[tile_m + srow] * K;
        else            arow_f = Af + (long)bz * A_bstride + (long)(tile_m + srow) * K;
    } else {
        arow_h = (const unsigned short*)Abase + (long)bz * A_bstride + (long)(tile_m + srow) * K;
    }
    const unsigned short* brow_h = nullptr;
    const float* csrc = nullptr;
    if (circ_src) csrc = circ_src + bz * 512;
    else brow_h = Bmat_h + (long)(tile_n + srow) * K;

    f32x4 zero4 = {0.f, 0.f, 0.f, 0.f};
    f32x4 acc[4][4];
    #pragma unroll
    for (int mi = 0; mi < 4; mi++)
        #pragma unroll
        for (int ni = 0; ni < 4; ni++) acc[mi][ni] = zero4;

    const int fr = lane & 15;
    const int fq = (lane >> 4) * 8;

    for (int kc = 0; kc < K; kc += 32) {
        __syncthreads();
        if (a_f32) {
            float4 u0 = *(const float4*)(arow_f + kc + skc);
            float4 u1 = *(const float4*)(arow_f + kc + skc + 4);
            float4 u2 = *(const float4*)(arow_f + kc + skc + 8);
            float4 u3 = *(const float4*)(arow_f + kc + skc + 12);
            unsigned short tmp[16] __attribute__((aligned(16)));
            tmp[0] = f2bf(u0.x); tmp[1] = f2bf(u0.y); tmp[2]  = f2bf(u0.z); tmp[3]  = f2bf(u0.w);
            tmp[4] = f2bf(u1.x); tmp[5] = f2bf(u1.y); tmp[6]  = f2bf(u1.z); tmp[7]  = f2bf(u1.w);
            tmp[8] = f2bf(u2.x); tmp[9] = f2bf(u2.y); tmp[10] = f2bf(u2.z); tmp[11] = f2bf(u2.w);
            tmp[12] = f2bf(u3.x); tmp[13] = f2bf(u3.y); tmp[14] = f2bf(u3.z); tmp[15] = f2bf(u3.w);
            *(uint4*)&Asm[srow * 40 + skc]     = *(const uint4*)tmp;
            *(uint4*)&Asm[srow * 40 + skc + 8] = *(const uint4*)(tmp + 8);
        } else {
            *(uint4*)&Asm[srow * 40 + skc]     = *(const uint4*)(arow_h + kc + skc);
            *(uint4*)&Asm[srow * 40 + skc + 8] = *(const uint4*)(arow_h + kc + skc + 8);
        }
        if (csrc) {
            unsigned short tmp[16] __attribute__((aligned(16)));
            int n_abs = tile_n + srow;
            #pragma unroll
            for (int j = 0; j < 16; j++) {
                int k_abs = kc + skc + j;
                tmp[j] = f2bf(csrc[(k_abs - n_abs) & 511]);
            }
            *(uint4*)&Bsm[srow * 40 + skc]     = *(const uint4*)tmp;
            *(uint4*)&Bsm[srow * 40 + skc + 8] = *(const uint4*)(tmp + 8);
        } else {
            *(uint4*)&Bsm[srow * 40 + skc]     = *(const uint4*)(brow_h + kc + skc);
            *(uint4*)&Bsm[srow * 40 + skc + 8] = *(const uint4*)(brow_h + kc + skc + 8);
        }
        __syncthreads();
        bf16x8 av[4], bv[4];
        #pragma unroll
        for (int mi = 0; mi < 4; mi++)
            av[mi] = *(const bf16x8*)&Asm[(wm + mi * 16 + fr) * 40 + fq];
        #pragma unroll
        for (int ni = 0; ni < 4; ni++)
            bv[ni] = *(const bf16x8*)&Bsm[(wn + ni * 16 + fr) * 40 + fq];
        #pragma unroll
        for (int mi = 0; mi < 4; mi++)
            #pragma unroll
            for (int ni = 0; ni < 4; ni++)
                acc[mi][ni] = __builtin_amdgcn_mfma_f32_16x16x32_bf16(
                    av[mi], bv[ni], acc[mi][ni], 0, 0, 0);
    }

    #pragma unroll
    for (int mi = 0; mi < 4; mi++) {
        #pragma unroll
        for (int ni = 0; ni < 4; ni++) {
            #pragma unroll
            for (int rg = 0; rg < 4; rg++) {
                int row = tile_m + wm + mi * 16 + (lane >> 4) * 4 + rg;
                int col = tile_n + wn + ni * 16 + (lane & 15);
                float v = acc[mi][ni][rg];
                if (bias) v += bias[col];
                if (act == 1) v = fast_tanh(v);
                long oidx = (long)bz * out_bstride + (long)row * N + col;
                if (outb) outb[oidx] = f2bf(v);
                else outf[oidx] = v;
            }
        }
    }
}

// ---------------------------------------------------------------------------
// Persistent LSTM recurrence, 64 blocks x 512 threads (8 waves). R12-exact.
// Partition: clique cq = bid&7 (-> one XCD under round-robin dispatch),
// member nbp = bid>>3 (0..7). Clique owns batches [cq*8,+8); member owns
// h-cols [nbp*64,+64) => 256 W_hh rows in registers (wfrag[2][16]/lane).
// Per step: poll 2048 dwords of Hs[cq*8..+8][t-1][*] (4 dwords/thread),
// stage to hsm rows 0..7 (rows 8..15 zero pad for MFMA M=16), 32 MFMAs/wave
// (2 N-frags x 16 k, 4 indep chains each), zl scatter, gate math on threads
// 0..255 (8 batches x 32 col-pairs), publish 256 dwords.
// Sync: NO flags, NO fences; sentinel-filled Hs; relaxed-agent dword ops.
// ---------------------------------------------------------------------------
#define WSTRIDE 520
#define ZL(g,r,d) zl[((g)*8+(r))*65+(d)]

__global__ __launch_bounds__(512, 2)
void persistent_lstm(const float* __restrict__ Whh,         // f32 [2048][512]
                     const unsigned short* __restrict__ Zx, // bf16 [16384][2048]
                     unsigned int* __restrict__ Hsu)        // Hs as dwords [64*256*256]
{
    __shared__ __align__(16) unsigned short hsm[16 * WSTRIDE];  // 16,640 B
    __shared__ float zl[4 * 8 * 65];                            //  8,320 B

    const int cq  = blockIdx.x & 7;   // clique id (== XCD under RR dispatch)
    const int nbp = blockIdx.x >> 3;  // column-owner within clique, 0..7
    const int tid = threadIdx.x;
    const int w = tid >> 6;        // 0..7
    const int lane = tid & 63;
    const int fr = lane & 15;
    const int fq = (lane >> 4) * 8;
    const int g = w >> 1;          // gate 0..3 (i,f,g,o)
    const int f = w & 1;           // 32-col half within member's 64 cols

    // ---- one-time: this wave's 32 W_hh rows into registers (2 frags) ----
    bf16x8 wfrag[2][16];
    #pragma unroll
    for (int n = 0; n < 2; n++) {
        const float* wrow = Whh + (long)(g * 512 + nbp * 64 + f * 32 + n * 16 + fr) * 512;
        #pragma unroll
        for (int c = 0; c < 16; c++) {
            int k0 = c * 32 + fq;
            float4 u0 = *(const float4*)(wrow + k0);
            float4 u1 = *(const float4*)(wrow + k0 + 4);
            unsigned short tmp[8] __attribute__((aligned(16)));
            tmp[0] = f2bf(u0.x); tmp[1] = f2bf(u0.y); tmp[2] = f2bf(u0.z); tmp[3] = f2bf(u0.w);
            tmp[4] = f2bf(u1.x); tmp[5] = f2bf(u1.y); tmp[6] = f2bf(u1.z); tmp[7] = f2bf(u1.w);
            wfrag[n][c] = *(const bf16x8*)tmp;
        }
    }

    // zero hsm once (rows 8..15 stay zero = MFMA pad rows). Visible to all
    // threads after the first barrier (S2 of t=0) before any hsm read (t=1).
    for (int i = tid; i < 16 * WSTRIDE / 2; i += 512)
        ((unsigned*)hsm)[i] = 0;

    // poll/staging ownership (R8-formula, 4 dwords): idx = k*512+tid,
    // row pr = idx>>8 (0..7), dword dp = idx&255
    int st_r[4], st_dp[4];
    #pragma unroll
    for (int k = 0; k < 4; k++) {
        int idx = k * 512 + tid;
        st_r[k] = idx >> 8;
        st_dp[k] = idx & 255;
    }

    // gate-math ownership (threads 0..255): batch grow 0..7, col pair d0
    const int grow = (tid & 255) >> 5;
    const int d0 = (tid & 31) * 2;
    const int b_own = cq * 8 + grow;
    const int dg = nbp * 64 + d0;
    float ca = 0.f, cb = 0.f;      // cell state in registers (threads < 256)

    f32x4 zero4 = {0.f, 0.f, 0.f, 0.f};

    for (int t = 0; t < T_; t++) {
        // Zx gate pre-activations: independent of h -> issue early
        unsigned zi_u = 0, zf_u = 0, zg_u = 0, zo_u = 0;
        if (tid < 256) {
            const long zb = ((long)b_own * T_ + t) * H4 + dg;
            zi_u = *(const unsigned*)&Zx[zb + 0 * 512];
            zf_u = *(const unsigned*)&Zx[zb + 1 * 512];
            zg_u = *(const unsigned*)&Zx[zb + 2 * 512];
            zo_u = *(const unsigned*)&Zx[zb + 3 * 512];
        }

        f32x4 an0 = zero4, an1 = zero4;
        if (t > 0) {
            // poll-stage h_{t-1}: 2048 dwords of Hs[cq*8..+8][t-1][*]
            unsigned vv[4];
            long ad[4];
            #pragma unroll
            for (int k = 0; k < 4; k++) {
                ad[k] = ((long)(cq * 8 + st_r[k]) * T_ + (t - 1)) * 256 + st_dp[k];
                vv[k] = __hip_atomic_load(Hsu + ad[k], __ATOMIC_RELAXED,
                                          __HIP_MEMORY_SCOPE_AGENT);
            }
            // check current values; if any pending, reload ALL (grouped) and
            // re-check the freshly loaded values in the same round.
            while (true) {
                bool pend = false;
                #pragma unroll
                for (int k = 0; k < 4; k++) pend |= (vv[k] == SENT);
                if (!__ballot(pend)) break;
                #pragma unroll
                for (int k = 0; k < 4; k++) {
                    vv[k] = __hip_atomic_load(Hsu + ad[k], __ATOMIC_RELAXED,
                                              __HIP_MEMORY_SCOPE_AGENT);
                }
            }
            #pragma unroll
            for (int k = 0; k < 4; k++) {
                *(unsigned*)&hsm[st_r[k] * WSTRIDE + st_dp[k] * 2] = vv[k];
            }
            __syncthreads();   // S1: hsm staged (also fences prev-iter zl reads)
            // z_frags = h_{t-1}[16x512 padded] @ Wfrags^T : 2 x 16 MFMAs,
            // 4 independent accumulator chains per frag, shared A loads
            const unsigned short* arow = hsm + fr * WSTRIDE;
            f32x4 a0[4] = {zero4, zero4, zero4, zero4};
            f32x4 a1[4] = {zero4, zero4, zero4, zero4};
            #pragma unroll
            for (int c = 0; c < 16; c += 4) {
                bf16x8 x0 = *(const bf16x8*)(arow + (c + 0) * 32 + fq);
                bf16x8 x1 = *(const bf16x8*)(arow + (c + 1) * 32 + fq);
                bf16x8 x2 = *(const bf16x8*)(arow + (c + 2) * 32 + fq);
                bf16x8 x3 = *(const bf16x8*)(arow + (c + 3) * 32 + fq);
                a0[0] = __builtin_amdgcn_mfma_f32_16x16x32_bf16(x0, wfrag[0][c + 0], a0[0], 0, 0, 0);
                a0[1] = __builtin_amdgcn_mfma_f32_16x16x32_bf16(x1, wfrag[0][c + 1], a0[1], 0, 0, 0);
                a0[2] = __builtin_amdgcn_mfma_f32_16x16x32_bf16(x2, wfrag[0][c + 2], a0[2], 0, 0, 0);
                a0[3] = __builtin_amdgcn_mfma_f32_16x16x32_bf16(x3, wfrag[0][c + 3], a0[3], 0, 0, 0);
                a1[0] = __builtin_amdgcn_mfma_f32_16x16x32_bf16(x0, wfrag[1][c + 0], a1[0], 0, 0, 0);
                a1[1] = __builtin_amdgcn_mfma_f32_16x16x32_bf16(x1, wfrag[1][c + 1], a1[1], 0, 0, 0);
                a1[2] = __builtin_amdgcn_mfma_f32_16x16x32_bf16(x2, wfrag[1][c + 2], a1[2], 0, 0, 0);
                a1[3] = __builtin_amdgcn_mfma_f32_16x16x32_bf16(x3, wfrag[1][c + 3], a1[3], 0, 0, 0);
            }
            an0 = (a0[0] + a0[1]) + (a0[2] + a0[3]);
            an1 = (a1[0] + a1[1]) + (a1[2] + a1[3]);
        }
        // scatter z to LDS (C/D: col=lane&15, row=(lane>>4)*4+reg);
        // only batch rows 0..7 are real -> lanes 0..31
        if (lane < 32) {
            const int rb = (lane >> 4) * 4;           // 0 or 4
            const int cl = f * 32 + (lane & 15);
            #pragma unroll
            for (int rg = 0; rg < 4; rg++) {
                ZL(g, rb + rg, cl)      = an0[rg];
                ZL(g, rb + rg, cl + 16) = an1[rg];
            }
        }
        __syncthreads();       // S2: zl complete (and hsm reads drained)
        // gate math on threads 0..255 (wave-uniform branch)
        if (tid < 256) {
            float zi0 = ZL(0, grow, d0)     + bf2f_lo(zi_u);
            float zi1 = ZL(0, grow, d0 + 1) + bf2f_hi(zi_u);
            float zf0 = ZL(1, grow, d0)     + bf2f_lo(zf_u);
            float zf1 = ZL(1, grow, d0 + 1) + bf2f_hi(zf_u);
            float zg0 = ZL(2, grow, d0)     + bf2f_lo(zg_u);
            float zg1 = ZL(2, grow, d0 + 1) + bf2f_hi(zg_u);
            float zo0 = ZL(3, grow, d0)     + bf2f_lo(zo_u);
            float zo1 = ZL(3, grow, d0 + 1) + bf2f_hi(zo_u);

            ca = fast_sigmoid(zf0) * ca + fast_sigmoid(zi0) * fast_tanh(zg0);
            cb = fast_sigmoid(zf1) * cb + fast_sigmoid(zi1) * fast_tanh(zg1);
            float h0 = fast_sigmoid(zo0) * fast_tanh(ca);
            float h1 = fast_sigmoid(zo1) * fast_tanh(cb);

            unsigned hp = (unsigned)f2bf(h0) | ((unsigned)f2bf(h1) << 16);
            // publish: history and exchange in one store (write-through)
            __hip_atomic_store(Hsu + ((long)b_own * T_ + t) * 256 + nbp * 32 + (tid & 31),
                               hp, __ATOMIC_RELAXED, __HIP_MEMORY_SCOPE_AGENT);
        }
        // no trailing sync: S1 of the next iteration protects zl reuse
    }
}

// ---------------------------------------------------------------------------
// tail_kernel: fused attn_r + hstar + out. One block per batch b (256 thr).
// Phase 1: single-pass online softmax over t + weighted Hs sum -> rs[512]
//   (16-t LDS chunks, coalesced loads; apre+Hs read ONCE).
// Phase 2: h_star[d] = tanh(w_p[d].rs + w_x[d].hts) -> hsr[512] (LDS only).
// Phase 3: logits + softmax -> out[b].
// ---------------------------------------------------------------------------
__global__ __launch_bounds__(256)
void tail_kernel(const float* __restrict__ apre,
                 const unsigned short* __restrict__ Hs,
                 const float* __restrict__ w_p,
                 const float* __restrict__ w_x,
                 const float* __restrict__ w_f,
                 const float* __restrict__ b_f,
                 float* __restrict__ out)
{
    __shared__ __align__(16) float apc[16 * 512];
    __shared__ __align__(16) unsigned short hc[16 * 512];
    __shared__ float rs[512];
    __shared__ float hts[512];
    __shared__ float hsr[512];
    __shared__ float lg[512];
    __shared__ float red[8];

    const int b = blockIdx.x, tid = threadIdx.x;
    const int d1 = tid + 256;
    const float* apb = apre + (long)b * T_ * D_;
    const unsigned short* hpb = Hs + (long)b * T_ * D_;

    float mx0 = -3.0e38f, sm0 = 0.f, ac0 = 0.f;
    float mx1 = -3.0e38f, sm1 = 0.f, ac1 = 0.f;

    for (int t0 = 0; t0 < T_; t0 += 16) {
        __syncthreads();
        for (int idx = tid; idx < 16 * 128; idx += 256) {
            int rr = idx >> 7, cc = (idx & 127) * 4;
            *(float4*)&apc[rr * 512 + cc] = *(const float4*)(apb + (long)(t0 + rr) * 512 + cc);
        }
        for (int idx = tid; idx < 16 * 64; idx += 256) {
            int rr = idx >> 6, cc = (idx & 63) * 8;
            *(uint4*)&hc[rr * 512 + cc] = *(const uint4*)(hpb + (long)(t0 + rr) * 512 + cc);
        }
        __syncthreads();
        #pragma unroll
        for (int i = 0; i < 16; i++) {
            float v0 = apc[i * 512 + tid];
            float h0 = bf2f(hc[i * 512 + tid]);
            if (v0 > mx0) {
                float fct = __expf(mx0 - v0);
                sm0 = sm0 * fct + 1.f;
                ac0 = ac0 * fct + h0;
                mx0 = v0;
            } else {
                float e = __expf(v0 - mx0);
                sm0 += e;
                ac0 += e * h0;
            }
            float v1 = apc[i * 512 + d1];
            float h1 = bf2f(hc[i * 512 + d1]);
            if (v1 > mx1) {
                float fct = __expf(mx1 - v1);
                sm1 = sm1 * fct + 1.f;
                ac1 = ac1 * fct + h1;
                mx1 = v1;
            } else {
                float e = __expf(v1 - mx1);
                sm1 += e;
                ac1 += e * h1;
            }
        }
    }
    rs[tid] = ac0 / sm0;
    rs[d1]  = ac1 / sm1;
    const long hlast = ((long)b * T_ + (T_ - 1)) * D_;
    hts[tid] = bf2f(Hs[hlast + tid]);
    hts[d1]  = bf2f(Hs[hlast + d1]);
    __syncthreads();

    for (int d = tid; d < 512; d += 256) {
        const float* wp = w_p + (long)d * D_;
        const float* wx = w_x + (long)d * D_;
        float acc = 0.f;
        for (int e = 0; e < 512; e += 4) {
            float4 p1 = *(const float4*)(wp + e);
            float4 p2 = *(const float4*)(wx + e);
            acc += p1.x * rs[e] + p1.y * rs[e + 1] + p1.z * rs[e + 2] + p1.w * rs[e + 3];
            acc += p2.x * hts[e] + p2.y * hts[e + 1] + p2.z * hts[e + 2] + p2.w * hts[e + 3];
        }
        hsr[d] = fast_tanh(acc);
    }
    __syncthreads();

    for (int d = tid; d < 512; d += 256) {
        const float* wr = w_f + (long)d * D_;
        float acc = b_f[d];
        for (int e = 0; e < 512; e += 4) {
            float4 p = *(const float4*)(wr + e);
            acc += p.x * hsr[e] + p.y * hsr[e + 1] + p.z * hsr[e + 2] + p.w * hsr[e + 3];
        }
        lg[d] = acc;
    }
    __syncthreads();
    float m0 = fmaxf(lg[tid], lg[d1]);
    for (int off = 32; off > 0; off >>= 1) m0 = fmaxf(m0, __shfl_down(m0, off, 64));
    if ((tid & 63) == 0) red[tid >> 6] = m0;
    __syncthreads();
    float bmax = fmaxf(fmaxf(red[0], red[1]), fmaxf(red[2], red[3]));
    float e0 = __expf(lg[tid] - bmax);
    float e1 = __expf(lg[d1] - bmax);
    float s0 = e0 + e1;
    for (int off = 32; off > 0; off >>= 1) s0 += __shfl_down(s0, off, 64);
    if ((tid & 63) == 0) red[4 + (tid >> 6)] = s0;
    __syncthreads();
    float inv = 1.f / (red[4] + red[5] + red[6] + red[7]);
    out[b * D_ + tid] = e0 * inv;
    out[b * D_ + d1]  = e1 * inv;
}

// ---------------------------------------------------------------------------
extern "C" void kernel_launch(void* const* d_in, const int* in_sizes, int n_in,
                              void* d_out, int out_size, void* d_ws, size_t ws_size,
                              hipStream_t stream)
{
    (void)in_sizes; (void)n_in; (void)out_size;

    const int* x = (const int*)d_in[0];
    const int* s = (const int*)d_in[1];
    const float* embed  = (const float*)d_in[2];
    const float* W_ih   = (const float*)d_in[3];
    const float* W_hh   = (const float*)d_in[4];
    const float* b_lstm = (const float*)d_in[5];
    const float* w_y = (const float*)d_in[6];
    const float* w_t = (const float*)d_in[7];
    const float* w_p = (const float*)d_in[8];
    const float* w_x = (const float*)d_in[9];
    const float* w_f = (const float*)d_in[10];
    const float* b_f = (const float*)d_in[11];

    // Workspace (overlaid):
    //   [0,64MiB)   phase1: Zx bf16 [16384][2048]
    //               phase2: apre f32 @0, mbuf bf16 @32MiB, Ybuf bf16 @48MiB
    //   [64MiB,+16MiB) Hs bf16 (exchange; sentinel-filled)
    //   @86114304: s_norm
    //   @86507520: Wcat_bf = bf16 [W_ih | w_y | w_t]  (3 MiB)
    //   @89653248: Ebf bf16 [16384][512] (16 MiB) -- only if ws_size allows
    char* ws = (char*)d_ws;
    unsigned short* Zx   = (unsigned short*)(ws + 0);
    float*          apre = (float*)(ws + 0);
    unsigned short* mbuf = (unsigned short*)(ws + 33554432);
    unsigned short* Ybuf = (unsigned short*)(ws + 50331648);
    unsigned short* Hs   = (unsigned short*)(ws + 67108864);
    float* s_norm = (float*)(ws + 86114304);
    unsigned short* Wcat = (unsigned short*)(ws + 86507520);
    unsigned short* Wih_bf = Wcat;
    unsigned short* wy_bf  = Wcat + 1048576;
    unsigned short* wt_bf  = Wcat + 1310720;
    unsigned short* Ebf  = (unsigned short*)(ws + 89653248);
    const int use_ebf = (ws_size >= (size_t)89653248 + 16777216u);

    // 0) fused prep: Hs sentinel fill | weight conv | embed gather-conv |
    //    aspect norm. One launch, 7682 blocks.
    prep_kernel<<<dim3(7682), dim3(256), 0, stream>>>(
        x, s, embed, W_ih, w_y, w_t, Wcat, Ebf, (uint4*)Hs, s_norm, use_ebf);

    // 1) G1: Zx = embed[x] @ W_ih^T + b_lstm  (M=16384, N=2048, K=512)
    if (use_ebf)
        gemm_bt<<<dim3(16, 128, 1), dim3(256), 0, stream>>>(
            Ebf, 0, nullptr, Wih_bf, nullptr, b_lstm, Zx, nullptr,
            2048, 512, 0L, 0L, 0);
    else
        gemm_bt<<<dim3(16, 128, 1), dim3(256), 0, stream>>>(
            embed, 1, x, Wih_bf, nullptr, b_lstm, Zx, nullptr,
            2048, 512, 0L, 0L, 0);

    // 2) recurrence: ONE persistent kernel, 64 blocks x 512 threads
    persistent_lstm<<<dim3(64), dim3(512), 0, stream>>>(
        W_hh, Zx, (unsigned int*)Hs);

    // ---- phase 2: Zx dead; region reused for apre/mbuf/Ybuf ----

    // 3) G2: m[b] = Hs[b] @ circ(s_norm[b])^T  (M=256, N=512, K=512, 64 batches)
    gemm_bt<<<dim3(4, 2, 64), dim3(256), 0, stream>>>(
        Hs, 0, nullptr, nullptr, s_norm, nullptr, mbuf, nullptr,
        512, 512, (long)(T_ * D_), (long)(T_ * D_), 0);

    // 4) G3: Y = tanh(m @ w_y^T)  (M=16384, N=512, K=512)
    gemm_bt<<<dim3(4, 128, 1), dim3(256), 0, stream>>>(
        mbuf, 0, nullptr, wy_bf, nullptr, nullptr, Ybuf, nullptr,
        512, 512, 0L, 0L, 1);

    // 5) G4: apre = Y @ w_t^T
    gemm_bt<<<dim3(4, 128, 1), dim3(256), 0, stream>>>(
        Ybuf, 0, nullptr, wt_bf, nullptr, nullptr, nullptr, apre,
        512, 512, 0L, 0L, 0);

    // 6) fused tail: online softmax+r, h_star, logits+softmax (1 block/batch)
    tail_kernel<<<dim3(64), dim3(256), 0, stream>>>(
        apre, Hs, w_p, w_x, w_f, b_f, (float*)d_out);
}